// Round 11
// baseline (388.135 us; speedup 1.0000x reference)
//
#include <hip/hip_runtime.h>
#include <stdint.h>

#define BATCH 65536
#define FDIM 512
#define HDIM 256
#define NC 10
#define NREP 16

typedef short short8 __attribute__((ext_vector_type(8)));
typedef float f32x4 __attribute__((ext_vector_type(4)));

// ---- workspace layout (bytes) ----
// Fragment-tiled layout: tile (I=row/16, C=k/32) is 1KB at (I*nC + C)*1024;
// slot l = (row&15) | (((k>>3)&3)<<4) holds 8 bf16 (k = (l>>4)*8 .. +7).
#define OFF_FC0T   ((size_t)0)                          // 32 J x 16 C tiles
#define OFF_FC1T   (OFF_FC0T + (size_t)512*512*2)
#define OFF_WT     (OFF_FC1T + (size_t)512*512*2)       // 16 J x 16 C tiles
#define OFF_X4T    (OFF_WT   + (size_t)256*512*2)       // 4096 I x 16 C (64MB)
#define OFF_ACC    (OFF_X4T  + (size_t)BATCH*512*2)
#define SCAL_SUMSQ 0
#define SCAL_CE    16
#define SCAL_ACC   32
#define SCAL_L1    48
#define SCAL_CTR   64                     // completion counter (int)
#define SCAL_N     128
#define CNT_OFF    SCAL_N                 // NREP*16 floats
#define GSUM_OFF   (SCAL_N + NREP*16)     // NREP*5120 floats
#define ACC_FLOATS (GSUM_OFF + NREP*5120) // 82304 floats
#define OFF_W1T    (OFF_ACC + (size_t)ACC_FLOATS*4)     // 8 C-tiles x 1KB (w1 bf16, padded to 16 classes)

#define GLL(g,l) __builtin_amdgcn_global_load_lds((const __attribute__((address_space(1))) void*)(g), (__attribute__((address_space(3))) void*)(l), 16, 0, 0)

__device__ __forceinline__ unsigned short f2b(float f){
  unsigned u = __float_as_uint(f);
  u += 0x7FFFu + ((u >> 16) & 1u);
  return (unsigned short)(u >> 16);
}
__device__ __forceinline__ float b2f(unsigned short h){
  return __uint_as_float(((unsigned)h) << 16);
}
__device__ __forceinline__ unsigned pk2b(float f0, float f1){
  unsigned u0 = __float_as_uint(f0) + 0x8000u;
  unsigned u1 = __float_as_uint(f1) + 0x8000u;
  return __builtin_amdgcn_perm(u1, u0, 0x07060302u);
}
__device__ __forceinline__ float ald(const float* p){
  return __hip_atomic_load(p, __ATOMIC_RELAXED, __HIP_MEMORY_SCOPE_AGENT);
}

// ---- K0: setup — weight prep (0..335), zero (336..416), class counts (417..432)
// (xcast ELIMINATED: k_gemm12 now reads f32 x directly and converts in-staging)
__global__ __launch_bounds__(256) void k_setup(
    const float* __restrict__ fc0, const float* __restrict__ fc1,
    const float* __restrict__ w,   const float* __restrict__ w1,
    const int* __restrict__ y,
    unsigned short* __restrict__ fc0T, unsigned short* __restrict__ fc1T,
    unsigned short* __restrict__ wT,   unsigned short* __restrict__ w1T,
    float* __restrict__ accb)
{
  int blk = blockIdx.x, t = threadIdx.x;
  if (blk < 336){
    int i = blk*256 + t;
    float l1v = 0.f;
    if (i < 32768){                       // fc0 [k][512] -> tiled
      int n4 = i&15, m = (i>>4)&3, C = (i>>6)&15, J = i>>10;
      int n = J*16+n4, k8 = C*4+m;
      unsigned short o[8];
      #pragma unroll
      for (int j=0;j<8;++j){ float v = fc0[(size_t)(k8*8+j)*512 + n]; o[j]=f2b(v); l1v += fabsf(v); }
      *(short8*)&fc0T[(size_t)(J*16+C)*512 + (i&63)*8] = *(short8*)o;
    } else if (i < 65536){                // fc1
      int j0 = i - 32768;
      int n4 = j0&15, m = (j0>>4)&3, C = (j0>>6)&15, J = j0>>10;
      int n = J*16+n4, k8 = C*4+m;
      unsigned short o[8];
      #pragma unroll
      for (int j=0;j<8;++j){ float v = fc1[(size_t)(k8*8+j)*512 + n]; o[j]=f2b(v); l1v += fabsf(v); }
      *(short8*)&fc1T[(size_t)(J*16+C)*512 + (j0&63)*8] = *(short8*)o;
    } else if (i < 81920){                // w [k][256]
      int j0 = i - 65536;
      int n4 = j0&15, m = (j0>>4)&3, C = (j0>>6)&15, J = j0>>10;
      int n = J*16+n4, k8 = C*4+m;
      unsigned short o[8];
      #pragma unroll
      for (int j=0;j<8;++j){ float v = w[(size_t)(k8*8+j)*256 + n]; o[j]=f2b(v); l1v += fabsf(v); }
      *(short8*)&wT[(size_t)(J*16+C)*512 + (j0&63)*8] = *(short8*)o;
    } else if (i < 86016){                // w1 -> B-fragment tiles (16 classes padded), + L1
      int j0 = i - 81920;                 // 0..4095, one bf16 each
      int C = j0 >> 9, l = (j0 >> 3) & 63, e = j0 & 7;
      int n = l & 15, k = C*32 + (l>>4)*8 + e;
      float v = (n < NC) ? w1[k*NC + n] : 0.f;
      w1T[C*512 + l*8 + e] = f2b(v);
      if (n < NC) l1v = fabsf(v);
    }
    for (int off = 32; off; off >>= 1) l1v += __shfl_down(l1v, off);
    if ((t & 63) == 0 && l1v != 0.f)
      atomicAdd(&accb[SCAL_L1 + (blk & (NREP-1))], l1v);
    return;
  }
  if (blk < 417){
    int base = (blk - 336)*1024;
    #pragma unroll
    for (int j=0;j<4;++j){
      int idx = base + j*256 + t;
      // exclude CNT region [CNT_OFF, CNT_OFF+256): fully written by cnt blocks
      if (idx < ACC_FLOATS && (idx < CNT_OFF || idx >= CNT_OFF + NREP*16))
        accb[idx] = 0.f;
    }
    return;
  }
  {
    // class counts: 16 blocks, 4096 labels each, private gcnt slot
    __shared__ float cntS[16];
    int b = blk - 417;
    if (t < 16) cntS[t] = 0.f;
    __syncthreads();
    int base = b*4096;
    for (int i = t; i < 4096; i += 256) atomicAdd(&cntS[y[base+i]], 1.f);
    __syncthreads();
    if (t < 16) accb[CNT_OFF + b*16 + t] = cntS[t];
  }
}

// ---------------------------------------------------------------------------
// K1: dual GEMM at 2 blocks/CU, A read DIRECTLY from f32 x (no xT pass).
// Block = 128 rows x 128 cols x {fc0,fc1}; 8 waves (2r x 4c); BK=32 (16 Kt);
// LDS 64KB: dbuf 2x24KB (A 8K + B0 8K + B1 8K) + epilogue headroom.
// A-staging: thread (wv,lane) owns fragment slot (tile wv, row=ln, kgrp=quad):
//   one 32B f32 read (4 lanes cover each 128B line), 4x pk2b, 1 ds_write_b128.
// B via GLL from pre-tiled weights. vmcnt(0)+lgkmcnt(0) per K-tile, 1 barrier.
// ---------------------------------------------------------------------------
__global__ __launch_bounds__(512, 4) void k_gemm12(
    const float* __restrict__ x,
    const unsigned short* __restrict__ fc0T,
    const unsigned short* __restrict__ fc1T,
    const int* __restrict__ y,
    unsigned short* __restrict__ x4T,
    float* __restrict__ accb)
{
  extern __shared__ __align__(16) char ldsd[];   // 65536 dynamic
  float* scal = accb;
  float* gsum = accb + GSUM_OFF;

  int blk = blockIdx.x;
  int wg = (blk & 7)*256 + (blk >> 3);           // bijective XCD chunking (2048%8==0)
  int rowblk = wg >> 2;                          // 0..511 (128 rows each)
  int colblk = wg & 3;                           // 0..3   (128 cols each)

  int t = threadIdx.x;
  int wv = t >> 6, lane = t & 63, ln = lane & 15, quad = lane >> 4;
  int wr = wv >> 2, wc = wv & 3;                 // 2 x 4 wave grid

  const char* b0b = (const char*)fc0T;
  const char* b1b = (const char*)fc1T;
  // this thread's A-source row base (row = rowblk*128 + wv*16 + ln)
  const float* arow = x + (size_t)(rowblk*128 + wv*16 + ln)*FDIM + quad*8;

  const f32x4 zv = {0.f,0.f,0.f,0.f};
  f32x4 acc1[4][2], acc2[4][2];
  #pragma unroll
  for (int m=0;m<4;++m){ acc1[m][0]=zv; acc1[m][1]=zv; acc2[m][0]=zv; acc2[m][1]=zv; }

  short8 a[4], b0r[2], b1r[2];

  // prologue: stage kt=0 into buf0
  {
    float4 va0 = *(const float4*)(arow);
    float4 va1 = *(const float4*)(arow + 4);
    GLL(b0b + (((size_t)((colblk*8+wv)*16 + 0)) << 10) + lane*16, ldsd +  8192 + (wv<<10) + lane*16);
    GLL(b1b + (((size_t)((colblk*8+wv)*16 + 0)) << 10) + lane*16, ldsd + 16384 + (wv<<10) + lane*16);
    unsigned o[4];
    o[0] = pk2b(va0.x, va0.y); o[1] = pk2b(va0.z, va0.w);
    o[2] = pk2b(va1.x, va1.y); o[3] = pk2b(va1.z, va1.w);
    *(short8*)(ldsd + (wv<<10) + lane*16) = *(short8*)o;
    asm volatile("s_waitcnt vmcnt(0) lgkmcnt(0)" ::: "memory");
    __builtin_amdgcn_sched_barrier(0);
    __builtin_amdgcn_s_barrier();
  }

  #pragma unroll
  for (int kt = 0; kt < 16; ++kt){
    char* cur = ldsd + ((kt & 1) ? 24576 : 0);
    char* nxt = ldsd + ((kt & 1) ? 0 : 24576);
    float4 va0, va1;
    if (kt < 15){
      va0 = *(const float4*)(arow + (kt+1)*32);
      va1 = *(const float4*)(arow + (kt+1)*32 + 4);
      GLL(b0b + (((size_t)((colblk*8+wv)*16 + kt+1)) << 10) + lane*16, nxt +  8192 + (wv<<10) + lane*16);
      GLL(b1b + (((size_t)((colblk*8+wv)*16 + kt+1)) << 10) + lane*16, nxt + 16384 + (wv<<10) + lane*16);
    }
    #pragma unroll
    for (int m=0;m<4;++m)
      a[m] = *(const short8*)(cur + ((wr*4+m)<<10) + lane*16);
    #pragma unroll
    for (int n=0;n<2;++n){
      b0r[n] = *(const short8*)(cur +  8192 + ((wc*2+n)<<10) + lane*16);
      b1r[n] = *(const short8*)(cur + 16384 + ((wc*2+n)<<10) + lane*16);
    }
    asm volatile("s_waitcnt lgkmcnt(0)" ::: "memory");
    __builtin_amdgcn_sched_barrier(0);
    __builtin_amdgcn_s_setprio(1);
    #pragma unroll
    for (int n=0;n<2;++n)
      #pragma unroll
      for (int m=0;m<4;++m){
        acc1[m][n] = __builtin_amdgcn_mfma_f32_16x16x32_bf16(a[m], b0r[n], acc1[m][n], 0,0,0);
        acc2[m][n] = __builtin_amdgcn_mfma_f32_16x16x32_bf16(a[m], b1r[n], acc2[m][n], 0,0,0);
      }
    __builtin_amdgcn_s_setprio(0);
    if (kt < 15){
      unsigned o[4];
      o[0] = pk2b(va0.x, va0.y); o[1] = pk2b(va0.z, va0.w);
      o[2] = pk2b(va1.x, va1.y); o[3] = pk2b(va1.z, va1.w);
      *(short8*)(nxt + (wv<<10) + lane*16) = *(short8*)o;
      asm volatile("s_waitcnt vmcnt(0) lgkmcnt(0)" ::: "memory");
    }
    __builtin_amdgcn_sched_barrier(0);
    __builtin_amdgcn_s_barrier();
  }

  // ---- epilogue: residual x (f32->bf16, same rounding as before) -> [0,32K);
  //      x4 bf16 -> [32K,64K)
  #pragma unroll
  for (int c = 0; c < 4; ++c){
    const float* rsrc = arow + (colblk*4 + c)*32;
    float4 v0 = *(const float4*)rsrc;
    float4 v1 = *(const float4*)(rsrc + 4);
    unsigned o[4];
    o[0] = pk2b(v0.x, v0.y); o[1] = pk2b(v0.z, v0.w);
    o[2] = pk2b(v1.x, v1.y); o[3] = pk2b(v1.z, v1.w);
    *(short8*)(ldsd + ((wv*4 + c) << 10) + lane*16) = *(short8*)o;
  }
  __syncthreads();

  unsigned short* resU = (unsigned short*)ldsd;
  unsigned short* x4U  = (unsigned short*)(ldsd + 32768);
  float sumsq = 0.f;
  #pragma unroll
  for (int m = 0; m < 4; ++m){
    #pragma unroll
    for (int n = 0; n < 2; ++n){
      #pragma unroll
      for (int r = 0; r < 4; ++r){
        int slot = (quad*4 + r) | ((n*2 + (ln>>3)) << 4);
        int idx = (((wr*4 + m)*4 + wc) << 9) + slot*8 + (ln & 7);
        float xv  = b2f(resU[idx]);
        float x1v = acc1[m][n][r];
        float x2v = fmaxf(acc2[m][n][r], 0.f);
        float gate = 1.f + 1.f/(1.f + __expf(-x1v));
        float x4v = fmaf(gate, x2v, xv);
        unsigned short ub = f2b(x4v);
        float fq = b2f(ub);
        sumsq = fmaf(fq, fq, sumsq);
        x4U[idx] = ub;
        acc1[m][n][r] = fq;               // keep quantized value for class-sum
      }
    }
  }
  for (int off = 32; off; off >>= 1) sumsq += __shfl_down(sumsq, off);
  __syncthreads();                         // res reads + x4 writes done; resU dead

  // ---- fused class-sum: per-thread masked-add over its 16 rows x 2 cols
  float cs[NC][2];
  #pragma unroll
  for (int c=0;c<NC;++c){ cs[c][0]=0.f; cs[c][1]=0.f; }
  {
    const int* yrow = y + rowblk*128 + wr*64;
    #pragma unroll
    for (int m = 0; m < 4; ++m){
      int yv[4];
      #pragma unroll
      for (int r = 0; r < 4; ++r) yv[r] = yrow[m*16 + quad*4 + r];
      #pragma unroll
      for (int r = 0; r < 4; ++r){
        float v0 = acc1[m][0][r], v1 = acc1[m][1][r];
        #pragma unroll
        for (int c = 0; c < NC; ++c){
          bool msk = (yv[r] == c);
          cs[c][0] += msk ? v0 : 0.f;
          cs[c][1] += msk ? v1 : 0.f;
        }
      }
    }
  }
  #pragma unroll
  for (int c = 0; c < NC; ++c)
    #pragma unroll
    for (int n = 0; n < 2; ++n){
      cs[c][n] += __shfl_xor(cs[c][n], 16);
      cs[c][n] += __shfl_xor(cs[c][n], 32);
    }
  if (lane < 16){
    size_t gb = (size_t)(blk & (NREP-1))*5120 + colblk*128 + wc*32 + ln;
    #pragma unroll
    for (int c = 0; c < NC; ++c){
      atomicAdd(&gsum[gb + c*512],      cs[c][0]);
      atomicAdd(&gsum[gb + c*512 + 16], cs[c][1]);
    }
  }

  float* red = (float*)ldsd;               // dead resU region
  if (lane == 0) red[wv] = sumsq;
  __syncthreads();
  if (t == 0){
    float s = 0.f;
    #pragma unroll
    for (int i=0;i<8;++i) s += red[i];
    atomicAdd(&scal[SCAL_SUMSQ + (blk & (NREP-1))], s);
  }
  // copy x4 LDS -> global (16B stores): 32 tiles
  #pragma unroll
  for (int r = 0; r < 4; ++r){
    int o = r*512 + t;
    int tile = o >> 6, off16 = o & 63;
    int Il = tile >> 2, Cl = tile & 3;
    size_t Ig = (size_t)rowblk*8 + Il;
    int Cg = colblk*4 + Cl;
    *(short8*)&x4T[((Ig*16 + Cg) << 9) + off16*8] =
      *(const short8*)&x4U[(tile << 9) + off16*8];
  }
}

// ---------------------------------------------------------------------------
// 8-phase fine-interleaved K-loop (round-3 verified) — used by k_gemm3_head.
// Block = 256 rows x (128 cols x 2 matrices); 8 waves; BK=64; double-buffered
// 128KB LDS (per buffer: A 32KB @0, B0 16KB @32K, B1 16KB @48K).
// ---------------------------------------------------------------------------

#define BARRIER() __builtin_amdgcn_s_barrier()
#define LGKM0() do{ asm volatile("s_waitcnt lgkmcnt(0)" ::: "memory"); \
                    __builtin_amdgcn_sched_barrier(0); }while(0)

#define RA(AB, C) do{                                                         \
  _Pragma("unroll") for (int m_=0;m_<8;++m_)                                  \
    a[m_] = *(const short8*)((AB) + (((wr*8+m_)*2 + (C))<<10) + lane*16);     \
}while(0)

#define RB(AB, MAT, C) do{                                                    \
  _Pragma("unroll") for (int n_=0;n_<2;++n_)                                  \
    bb[n_] = *(const short8*)((AB) + 32768 + (MAT)*16384 +                    \
                              (((wc*2+n_)*2 + (C))<<10) + lane*16);           \
}while(0)

#define MM16(ACC) do{                                                         \
  __builtin_amdgcn_s_setprio(1);                                              \
  _Pragma("unroll") for (int n_=0;n_<2;++n_)                                  \
  _Pragma("unroll") for (int m_=0;m_<8;++m_)                                  \
    ACC[m_][n_] = __builtin_amdgcn_mfma_f32_16x16x32_bf16(a[m_], bb[n_], ACC[m_][n_], 0,0,0); \
  __builtin_amdgcn_s_setprio(0);                                              \
}while(0)

#define SA(KT, C) do{                                                         \
  char* d_ = ldsd + (((KT)&1) ? 65536 : 0);                                   \
  _Pragma("unroll") for (int r_=0;r_<2;++r_){                                 \
    int I_ = wv + r_*8;                                                       \
    GLL(xb + (((size_t)((rowblk*16 + I_)*16 + (KT)*2 + (C))) << 10) + lane*16,\
        d_ + ((I_*2 + (C)) << 10) + lane*16);                                 \
  } }while(0)

#define SB(KT, C) do{                                                         \
  char* d_ = ldsd + (((KT)&1) ? 65536 : 0) + 32768;                           \
  GLL(b0b + (((size_t)((colblk*8 + wv)*16 + (KT)*2 + (C))) << 10) + lane*16,  \
      d_ + ((wv*2 + (C)) << 10) + lane*16);                                   \
  GLL(b1b + (((size_t)((colblk*8 + wv)*16 + (KT)*2 + (C))) << 10) + lane*16,  \
      d_ + 16384 + ((wv*2 + (C)) << 10) + lane*16);                           \
}while(0)

#define KLOOP() do{                                                           \
  SA(0,0); SB(0,0); SA(0,1); SB(0,1); SA(1,0); SB(1,0); SA(1,1);              \
  asm volatile("s_waitcnt vmcnt(6)" ::: "memory");                            \
  __builtin_amdgcn_sched_barrier(0);                                          \
  BARRIER();                                                                  \
  _Pragma("unroll")                                                           \
  for (int i = 0; i < 4; ++i){                                                \
    int kt0 = 2*i, kt1 = 2*i+1;                                               \
    char* Ab0 = ldsd + ((kt0 & 1) ? 65536 : 0);                               \
    char* Ab1 = ldsd + ((kt1 & 1) ? 65536 : 0);                               \
    RA(Ab0, 0); RB(Ab0, 0, 0);                                                \
    SB(kt1, 1);                                                               \
    BARRIER(); LGKM0(); MM16(acc1);                                           \
    BARRIER();                                                                \
    RB(Ab0, 1, 0);                                                            \
    if (i < 3) SA(kt0+2, 0);                                                  \
    BARRIER(); LGKM0(); MM16(acc2);                                           \
    BARRIER();                                                                \
    RA(Ab0, 1); RB(Ab0, 0, 1);                                                \
    if (i < 3) SB(kt0+2, 0);                                                  \
    BARRIER(); LGKM0(); MM16(acc1);                                           \
    BARRIER();                                                                \
    RB(Ab0, 1, 1);                                                            \
    if (i < 3) SA(kt0+2, 1);                                                  \
    BARRIER(); LGKM0(); MM16(acc2);                                           \
    if (i < 3) { asm volatile("s_waitcnt vmcnt(6)" ::: "memory"); }           \
    else       { asm volatile("s_waitcnt vmcnt(0)" ::: "memory"); }           \
    __builtin_amdgcn_sched_barrier(0);                                        \
    BARRIER();                                                                \
    RA(Ab1, 0); RB(Ab1, 0, 0);                                                \
    if (i < 3) SB(kt0+2, 1);                                                  \
    BARRIER(); LGKM0(); MM16(acc1);                                           \
    BARRIER();                                                                \
    RB(Ab1, 1, 0);                                                            \
    if (i < 3) SA(kt1+2, 0);                                                  \
    BARRIER(); LGKM0(); MM16(acc2);                                           \
    BARRIER();                                                                \
    RA(Ab1, 1); RB(Ab1, 0, 1);                                                \
    if (i < 3) SB(kt1+2, 0);                                                  \
    BARRIER(); LGKM0(); MM16(acc1);                                           \
    BARRIER();                                                                \
    RB(Ab1, 1, 1);                                                            \
    if (i < 3) SA(kt1+2, 1);                                                  \
    BARRIER(); LGKM0(); MM16(acc2);                                           \
    if (i < 3) { asm volatile("s_waitcnt vmcnt(6)" ::: "memory");             \
                 __builtin_amdgcn_sched_barrier(0); }                         \
    BARRIER();                                                                \
  }                                                                           \
}while(0)

// K2: h = relu(x4 @ w); logits = h @ w1; CE/argmax/acc; LAST block finalizes.
__global__ __launch_bounds__(512, 2) void k_gemm3_head(
    const unsigned short* __restrict__ x4T,
    const unsigned short* __restrict__ wT,
    const unsigned short* __restrict__ w1T,
    const int* __restrict__ y,
    float* __restrict__ accb,
    float* __restrict__ out)
{
  extern __shared__ __align__(16) char ldsd[];   // 131072 dynamic
  __shared__ float redc[8], reda[8];
  __shared__ int lastB;

  float* scal = accb;

  int blk = blockIdx.x;
  int rowblk = blk;                              // 256 rows each
  const int colblk = 0;

  int t = threadIdx.x;
  int wv = t >> 6, lane = t & 63, ln = lane & 15, quad = lane >> 4;
  int wr = wv >> 2, wc = wv & 3;
  int rep = (blk ^ (blk >> 4)) & (NREP-1);

  const char* xb  = (const char*)x4T;
  const char* b0b = (const char*)wT;                       // w cols 0..127 (J 0..7)
  const char* b1b = (const char*)wT + (size_t)128*1024;    // w cols 128..255 (J 8..15)

  const f32x4 zv = {0.f,0.f,0.f,0.f};
  f32x4 acc1[8][2], acc2[8][2];
  #pragma unroll
  for (int m=0;m<8;++m){ acc1[m][0]=zv; acc1[m][1]=zv; acc2[m][0]=zv; acc2[m][1]=zv; }

  short8 a[8], bb[2];

  KLOOP();

  // w1 B-fragments from global (8KB, L2-resident)
  short8 bw1[8];
  #pragma unroll
  for (int Ck = 0; Ck < 8; ++Ck)
    bw1[Ck] = *(const short8*)&w1T[Ck*512 + lane*8];

  // h = relu(acc) fragment-tiled into the (dead) full 128KB LDS
  unsigned short* transH = (unsigned short*)ldsd;
  #pragma unroll
  for (int m = 0; m < 8; ++m){
    #pragma unroll
    for (int n = 0; n < 2; ++n){
      #pragma unroll
      for (int r = 0; r < 4; ++r){
        int slot = (quad*4 + r) | ((n*2 + (ln>>3)) << 4);
        int e = ln & 7;
        int IhA = wr*8 + m;
        transH[((IhA*8 + wc)     << 9) + slot*8 + e] = f2b(fmaxf(acc1[m][n][r], 0.f));
        transH[((IhA*8 + 4 + wc) << 9) + slot*8 + e] = f2b(fmaxf(acc2[m][n][r], 0.f));
      }
    }
  }
  __syncthreads();

  // logits: each wave handles row-tiles Ih = wv*2 + {0,1}
  f32x4 alog[2] = {zv, zv};
  #pragma unroll
  for (int ih = 0; ih < 2; ++ih){
    int Ih = wv*2 + ih;
    #pragma unroll
    for (int Ck = 0; Ck < 8; ++Ck){
      short8 af = *(const short8*)&transH[((Ih*8 + Ck) << 9) + lane*8];
      alog[ih] = __builtin_amdgcn_mfma_f32_16x16x32_bf16(af, bw1[Ck], alog[ih], 0,0,0);
    }
  }

  // CE/argmax: row = blk*256 + Ih*16 + quad*4 + r, class = ln
  float ce_l = 0.f, acc_l = 0.f;
  #pragma unroll
  for (int ih = 0; ih < 2; ++ih){
    #pragma unroll
    for (int r = 0; r < 4; ++r){
      int grow = blk*256 + (wv*2 + ih)*16 + quad*4 + r;
      int yv = y[grow];
      float lg = (ln < NC) ? alog[ih][r] : -1e30f;
      float m = lg; int mi = ln;
      #pragma unroll
      for (int mk = 1; mk < 16; mk <<= 1){
        float om = __shfl_xor(m, mk); int oi = __shfl_xor(mi, mk);
        if (om > m || (om == m && oi < mi)){ m = om; mi = oi; }
      }
      float e  = (ln < NC) ? __expf(lg - m) : 0.f;
      float sy = (ln == yv) ? lg : 0.f;
      #pragma unroll
      for (int mk = 1; mk < 16; mk <<= 1){ e += __shfl_xor(e, mk); sy += __shfl_xor(sy, mk); }
      float lse = m + __logf(e);
      if (ln == 0){ ce_l += (lse - sy); acc_l += (mi == yv) ? 1.f : 0.f; }
    }
  }
  ce_l  += __shfl_down(ce_l, 16);  acc_l += __shfl_down(acc_l, 16);
  ce_l  += __shfl_down(ce_l, 32);  acc_l += __shfl_down(acc_l, 32);
  if (lane == 0){ redc[wv] = ce_l; reda[wv] = acc_l; }
  __syncthreads();
  if (t == 0){
    float c = 0.f, aa = 0.f;
    #pragma unroll
    for (int i=0;i<8;++i){ c += redc[i]; aa += reda[i]; }
    atomicAdd(&scal[SCAL_CE  + rep], c);
    atomicAdd(&scal[SCAL_ACC + rep], aa);
    __threadfence();
    int prev = atomicAdd((int*)(scal + SCAL_CTR), 1);
    lastB = (prev == (int)gridDim.x - 1);
  }
  __syncthreads();
  if (!lastB) return;

  // ---- merged k_final: last block reduces gsum/gcnt/scal -> out
  {
    const float* gsum = accb + GSUM_OFF;
    const float* gcnt = accb + CNT_OFF;
    float contrib = 0.f;
    for (int idx = t; idx < 5120; idx += 512){
      float S = 0.f;
      #pragma unroll
      for (int r = 0; r < NREP; ++r) S += ald(&gsum[(size_t)r*5120 + idx]);
      int c = idx >> 9;
      float cnt = 0.f;
      #pragma unroll
      for (int r = 0; r < NREP; ++r) cnt += ald(&gcnt[r*16 + c]);
      contrib += S*S / fmaxf(cnt, 1.f);
    }
    for (int off = 32; off; off >>= 1) contrib += __shfl_down(contrib, off);
    __syncthreads();                  // redc reusable
    if (lane == 0) redc[wv] = contrib;
    __syncthreads();
    if (t == 0){
      float var2 = 0.f;
      #pragma unroll
      for (int i=0;i<8;++i) var2 += redc[i];
      float sumsq=0.f, ce=0.f, accv=0.f, l1=0.f;
      for (int r=0;r<NREP;++r){
        sumsq += ald(&scal[SCAL_SUMSQ+r]);
        ce    += ald(&scal[SCAL_CE+r]);
        accv  += ald(&scal[SCAL_ACC+r]);
        l1    += ald(&scal[SCAL_L1+r]);
      }
      float var_loss = sumsq - var2;
      out[0] = ce/(float)BATCH + 1e-4f*l1 + 1e-3f*var_loss;
      out[1] = accv/(float)BATCH;
    }
  }
}

extern "C" void kernel_launch(void* const* d_in, const int* in_sizes, int n_in,
                              void* d_out, int out_size, void* d_ws, size_t ws_size,
                              hipStream_t stream){
  (void)in_sizes; (void)n_in; (void)out_size; (void)ws_size;
  const float* x   = (const float*)d_in[0];
  const int*   y   = (const int*)d_in[1];
  const float* fc0 = (const float*)d_in[2];
  const float* fc1 = (const float*)d_in[3];
  const float* w   = (const float*)d_in[4];
  const float* w1  = (const float*)d_in[5];
  char* ws = (char*)d_ws;
  unsigned short* fc0T = (unsigned short*)(ws + OFF_FC0T);
  unsigned short* fc1T = (unsigned short*)(ws + OFF_FC1T);
  unsigned short* wT   = (unsigned short*)(ws + OFF_WT);
  unsigned short* x4T  = (unsigned short*)(ws + OFF_X4T);
  unsigned short* w1T  = (unsigned short*)(ws + OFF_W1T);
  float* accb = (float*)(ws + OFF_ACC);

  static bool once = [](){
    hipFuncSetAttribute((const void*)k_gemm12,
                        hipFuncAttributeMaxDynamicSharedMemorySize, 65536);
    hipFuncSetAttribute((const void*)k_gemm3_head,
                        hipFuncAttributeMaxDynamicSharedMemorySize, 131072);
    return true;
  }();
  (void)once;

  k_setup<<<433, 256, 0, stream>>>(fc0, fc1, w, w1, y, fc0T, fc1T, wT, w1T, accb);
  k_gemm12<<<2048, 512, 65536, stream>>>(x, fc0T, fc1T, y, x4T, accb);
  k_gemm3_head<<<256, 512, 131072, stream>>>(x4T, wT, w1T, y, accb, (float*)d_out);
}

// Round 13
// 350.134 us; speedup vs baseline: 1.1085x; 1.1085x over previous
//
#include <hip/hip_runtime.h>
#include <stdint.h>

#define BATCH 65536
#define FDIM 512
#define HDIM 256
#define NC 10
#define NREP 16

typedef short short8 __attribute__((ext_vector_type(8)));
typedef float f32x4 __attribute__((ext_vector_type(4)));

// ---- workspace layout (bytes) ----
// Fragment-tiled layout: tile (I=row/16, C=k/32) is 1KB at (I*nC + C)*1024;
// slot l = (row&15) | (((k>>3)&3)<<4) holds 8 bf16 (k = (l>>4)*8 .. +7).
#define OFF_FC0T   ((size_t)0)                          // 32 J x 16 C tiles
#define OFF_FC1T   (OFF_FC0T + (size_t)512*512*2)
#define OFF_WT     (OFF_FC1T + (size_t)512*512*2)       // 16 J x 16 C tiles
#define OFF_XT     (OFF_WT   + (size_t)256*512*2)       // 4096 I x 16 C (64MB)
#define OFF_X4T    (OFF_XT   + (size_t)BATCH*512*2)     // 4096 I x 16 C (64MB)
#define OFF_ACC    (OFF_X4T  + (size_t)BATCH*512*2)
#define SCAL_SUMSQ 0
#define SCAL_CE    16
#define SCAL_ACC   32
#define SCAL_L1    48
#define SCAL_CTR   64                     // completion counter (int)
#define SCAL_N     128
#define CNT_OFF    SCAL_N                 // NREP*16 floats
#define GSUM_OFF   (SCAL_N + NREP*16)     // NREP*5120 floats
#define ACC_FLOATS (GSUM_OFF + NREP*5120) // 82304 floats
#define OFF_W1T    (OFF_ACC + (size_t)ACC_FLOATS*4)     // 8 C-tiles x 1KB (w1 bf16, padded to 16 classes)

#define GLL(g,l) __builtin_amdgcn_global_load_lds((const __attribute__((address_space(1))) void*)(g), (__attribute__((address_space(3))) void*)(l), 16, 0, 0)

__device__ __forceinline__ unsigned short f2b(float f){
  unsigned u = __float_as_uint(f);
  u += 0x7FFFu + ((u >> 16) & 1u);
  return (unsigned short)(u >> 16);
}
__device__ __forceinline__ float b2f(unsigned short h){
  return __uint_as_float(((unsigned)h) << 16);
}
__device__ __forceinline__ unsigned pk2b(float f0, float f1){
  unsigned u0 = __float_as_uint(f0) + 0x8000u;
  unsigned u1 = __float_as_uint(f1) + 0x8000u;
  return __builtin_amdgcn_perm(u1, u0, 0x07060302u);
}
__device__ __forceinline__ float ald(const float* p){
  return __hip_atomic_load(p, __ATOMIC_RELAXED, __HIP_MEMORY_SCOPE_AGENT);
}

// ---- K0: setup — xcast (0..2047), weight prep (2048..2383), zero (2384..2464),
//      class counts (2465..2480)
__global__ __launch_bounds__(256) void k_setup(
    const float* __restrict__ x,   const float* __restrict__ fc0,
    const float* __restrict__ fc1, const float* __restrict__ w,
    const float* __restrict__ w1,  const int* __restrict__ y,
    unsigned short* __restrict__ xT,   unsigned short* __restrict__ fc0T,
    unsigned short* __restrict__ fc1T, unsigned short* __restrict__ wT,
    unsigned short* __restrict__ w1T,  float* __restrict__ accb)
{
  int blk = blockIdx.x, t = threadIdx.x;
  if (blk < 2048){
    // x-cast via LDS transpose: contiguous 2KB-row reads AND contiguous 1KB
    // tile writes. LDS [16][520] bf16 (pad 8 shorts kills bank aliasing).
    __shared__ __align__(16) unsigned short xls[16*520];
    int wv = t >> 6, l = t & 63;
    #pragma unroll 1
    for (int it = 0; it < 2; ++it){
      int I = blk*2 + it;
      #pragma unroll
      for (int rr = 0; rr < 4; ++rr){
        int row = wv*4 + rr;
        const float* src = x + ((size_t)(I*16 + row))*FDIM + l*8;
        float4 v0 = *(const float4*)src;
        float4 v1 = *(const float4*)(src + 4);
        unsigned o[4];
        o[0] = pk2b(v0.x, v0.y); o[1] = pk2b(v0.z, v0.w);
        o[2] = pk2b(v1.x, v1.y); o[3] = pk2b(v1.z, v1.w);
        *(short8*)&xls[row*520 + l*8] = *(short8*)o;
      }
      __syncthreads();
      #pragma unroll
      for (int cc = 0; cc < 4; ++cc){
        int C = cc*4 + wv;
        short8 v = *(const short8*)&xls[(l & 15)*520 + C*32 + (l >> 4)*8];
        *(short8*)&xT[(((size_t)I*16 + C) << 9) + l*8] = v;
      }
      __syncthreads();
    }
    return;
  }
  if (blk < 2384){
    int i = (blk - 2048)*256 + t;
    float l1v = 0.f;
    if (i < 32768){                       // fc0 [k][512] -> tiled
      int n4 = i&15, m = (i>>4)&3, C = (i>>6)&15, J = i>>10;
      int n = J*16+n4, k8 = C*4+m;
      unsigned short o[8];
      #pragma unroll
      for (int j=0;j<8;++j){ float v = fc0[(size_t)(k8*8+j)*512 + n]; o[j]=f2b(v); l1v += fabsf(v); }
      *(short8*)&fc0T[(size_t)(J*16+C)*512 + (i&63)*8] = *(short8*)o;
    } else if (i < 65536){                // fc1
      int j0 = i - 32768;
      int n4 = j0&15, m = (j0>>4)&3, C = (j0>>6)&15, J = j0>>10;
      int n = J*16+n4, k8 = C*4+m;
      unsigned short o[8];
      #pragma unroll
      for (int j=0;j<8;++j){ float v = fc1[(size_t)(k8*8+j)*512 + n]; o[j]=f2b(v); l1v += fabsf(v); }
      *(short8*)&fc1T[(size_t)(J*16+C)*512 + (j0&63)*8] = *(short8*)o;
    } else if (i < 81920){                // w [k][256]
      int j0 = i - 65536;
      int n4 = j0&15, m = (j0>>4)&3, C = (j0>>6)&15, J = j0>>10;
      int n = J*16+n4, k8 = C*4+m;
      unsigned short o[8];
      #pragma unroll
      for (int j=0;j<8;++j){ float v = w[(size_t)(k8*8+j)*256 + n]; o[j]=f2b(v); l1v += fabsf(v); }
      *(short8*)&wT[(size_t)(J*16+C)*512 + (j0&63)*8] = *(short8*)o;
    } else if (i < 86016){                // w1 -> B-fragment tiles (16 classes padded), + L1
      int j0 = i - 81920;                 // 0..4095, one bf16 each
      int C = j0 >> 9, l = (j0 >> 3) & 63, e = j0 & 7;
      int n = l & 15, k = C*32 + (l>>4)*8 + e;
      float v = (n < NC) ? w1[k*NC + n] : 0.f;
      w1T[C*512 + l*8 + e] = f2b(v);
      if (n < NC) l1v = fabsf(v);
    }
    for (int off = 32; off; off >>= 1) l1v += __shfl_down(l1v, off);
    if ((t & 63) == 0 && l1v != 0.f)
      atomicAdd(&accb[SCAL_L1 + (blk & (NREP-1))], l1v);
    return;
  }
  if (blk < 2465){
    int base = (blk - 2384)*1024;
    #pragma unroll
    for (int j=0;j<4;++j){
      int idx = base + j*256 + t;
      // exclude CNT region [CNT_OFF, CNT_OFF+256): fully written by cnt blocks
      if (idx < ACC_FLOATS && (idx < CNT_OFF || idx >= CNT_OFF + NREP*16))
        accb[idx] = 0.f;
    }
    return;
  }
  {
    // class counts: 16 blocks, 4096 labels each, private gcnt slot
    __shared__ float cntS[16];
    int b = blk - 2465;
    if (t < 16) cntS[t] = 0.f;
    __syncthreads();
    int base = b*4096;
    for (int i = t; i < 4096; i += 256) atomicAdd(&cntS[y[base+i]], 1.f);
    __syncthreads();
    if (t < 16) accb[CNT_OFF + b*16 + t] = cntS[t];
  }
}

// ---------------------------------------------------------------------------
// K1: dual GEMM at 2 BLOCKS/CU (proven R10 form, session best). Block = 128
// rows x 128 cols x {fc0,fc1}; 8 waves (2r x 4c); BK=32 (16 K-tiles); LDS
// 64KB: double-buffered 2x24KB (A 8K + B0 8K + B1 8K) + 16KB epilogue
// headroom. m97-style loop: stage kt+1 early -> read+MFMA kt -> vmcnt(0) ->
// ONE barrier. Drain stall is covered by the sibling block on the same CU.
// ---------------------------------------------------------------------------
__global__ __launch_bounds__(512, 4) void k_gemm12(
    const unsigned short* __restrict__ xT,
    const unsigned short* __restrict__ fc0T,
    const unsigned short* __restrict__ fc1T,
    const int* __restrict__ y,
    unsigned short* __restrict__ x4T,
    float* __restrict__ accb)
{
  extern __shared__ __align__(16) char ldsd[];   // 65536 dynamic
  float* scal = accb;
  float* gsum = accb + GSUM_OFF;

  int blk = blockIdx.x;
  int wg = (blk & 7)*256 + (blk >> 3);           // bijective XCD chunking (2048%8==0)
  int rowblk = wg >> 2;                          // 0..511 (128 rows each)
  int colblk = wg & 3;                           // 0..3   (128 cols each)

  int t = threadIdx.x;
  int wv = t >> 6, lane = t & 63, ln = lane & 15, quad = lane >> 4;
  int wr = wv >> 2, wc = wv & 3;                 // 2 x 4 wave grid

  const char* xb  = (const char*)xT;
  const char* b0b = (const char*)fc0T;
  const char* b1b = (const char*)fc1T;

  const f32x4 zv = {0.f,0.f,0.f,0.f};
  f32x4 acc1[4][2], acc2[4][2];
  #pragma unroll
  for (int m=0;m<4;++m){ acc1[m][0]=zv; acc1[m][1]=zv; acc2[m][0]=zv; acc2[m][1]=zv; }

  short8 a[4], b0r[2], b1r[2];

  // prologue: stage kt=0 into buf0
  GLL(xb  + (((size_t)((rowblk*8+wv)*16 + 0)) << 10) + lane*16, ldsd +         (wv<<10) + lane*16);
  GLL(b0b + (((size_t)((colblk*8+wv)*16 + 0)) << 10) + lane*16, ldsd +  8192 + (wv<<10) + lane*16);
  GLL(b1b + (((size_t)((colblk*8+wv)*16 + 0)) << 10) + lane*16, ldsd + 16384 + (wv<<10) + lane*16);
  asm volatile("s_waitcnt vmcnt(0)" ::: "memory");
  __builtin_amdgcn_sched_barrier(0);
  __builtin_amdgcn_s_barrier();

  #pragma unroll
  for (int kt = 0; kt < 16; ++kt){
    char* cur = ldsd + ((kt & 1) ? 24576 : 0);
    char* nxt = ldsd + ((kt & 1) ? 0 : 24576);
    if (kt < 15){
      GLL(xb  + (((size_t)((rowblk*8+wv)*16 + kt+1)) << 10) + lane*16, nxt +         (wv<<10) + lane*16);
      GLL(b0b + (((size_t)((colblk*8+wv)*16 + kt+1)) << 10) + lane*16, nxt +  8192 + (wv<<10) + lane*16);
      GLL(b1b + (((size_t)((colblk*8+wv)*16 + kt+1)) << 10) + lane*16, nxt + 16384 + (wv<<10) + lane*16);
    }
    #pragma unroll
    for (int m=0;m<4;++m)
      a[m] = *(const short8*)(cur + ((wr*4+m)<<10) + lane*16);
    #pragma unroll
    for (int n=0;n<2;++n){
      b0r[n] = *(const short8*)(cur +  8192 + ((wc*2+n)<<10) + lane*16);
      b1r[n] = *(const short8*)(cur + 16384 + ((wc*2+n)<<10) + lane*16);
    }
    asm volatile("s_waitcnt lgkmcnt(0)" ::: "memory");
    __builtin_amdgcn_sched_barrier(0);
    __builtin_amdgcn_s_setprio(1);
    #pragma unroll
    for (int n=0;n<2;++n)
      #pragma unroll
      for (int m=0;m<4;++m){
        acc1[m][n] = __builtin_amdgcn_mfma_f32_16x16x32_bf16(a[m], b0r[n], acc1[m][n], 0,0,0);
        acc2[m][n] = __builtin_amdgcn_mfma_f32_16x16x32_bf16(a[m], b1r[n], acc2[m][n], 0,0,0);
      }
    __builtin_amdgcn_s_setprio(0);
    if (kt < 15){ asm volatile("s_waitcnt vmcnt(0)" ::: "memory"); }
    __builtin_amdgcn_sched_barrier(0);
    __builtin_amdgcn_s_barrier();
  }

  // ---- epilogue: residual x -> [0,32K); x4 bf16 -> [32K,64K)
  #pragma unroll
  for (int c = 0; c < 4; ++c){
    GLL(xb + (((size_t)((rowblk*8+wv)*16 + colblk*4 + c)) << 10) + lane*16,
        ldsd + ((wv*4 + c) << 10) + lane*16);
  }
  asm volatile("s_waitcnt vmcnt(0)" ::: "memory");
  __syncthreads();

  unsigned short* resU = (unsigned short*)ldsd;
  unsigned short* x4U  = (unsigned short*)(ldsd + 32768);
  float sumsq = 0.f;
  #pragma unroll
  for (int m = 0; m < 4; ++m){
    #pragma unroll
    for (int n = 0; n < 2; ++n){
      #pragma unroll
      for (int r = 0; r < 4; ++r){
        int slot = (quad*4 + r) | ((n*2 + (ln>>3)) << 4);
        int idx = (((wr*4 + m)*4 + wc) << 9) + slot*8 + (ln & 7);
        float xv  = b2f(resU[idx]);
        float x1v = acc1[m][n][r];
        float x2v = fmaxf(acc2[m][n][r], 0.f);
        float gate = 1.f + 1.f/(1.f + __expf(-x1v));
        float x4v = fmaf(gate, x2v, xv);
        unsigned short ub = f2b(x4v);
        float fq = b2f(ub);
        sumsq = fmaf(fq, fq, sumsq);
        x4U[idx] = ub;
        acc1[m][n][r] = fq;               // keep quantized value for class-sum
      }
    }
  }
  for (int off = 32; off; off >>= 1) sumsq += __shfl_down(sumsq, off);
  __syncthreads();                         // res reads + x4 writes done; resU dead

  // ---- fused class-sum: per-thread masked-add over its 16 rows x 2 cols
  float cs[NC][2];
  #pragma unroll
  for (int c=0;c<NC;++c){ cs[c][0]=0.f; cs[c][1]=0.f; }
  {
    const int* yrow = y + rowblk*128 + wr*64;
    #pragma unroll
    for (int m = 0; m < 4; ++m){
      int yv[4];
      #pragma unroll
      for (int r = 0; r < 4; ++r) yv[r] = yrow[m*16 + quad*4 + r];
      #pragma unroll
      for (int r = 0; r < 4; ++r){
        float v0 = acc1[m][0][r], v1 = acc1[m][1][r];
        #pragma unroll
        for (int c = 0; c < NC; ++c){
          bool msk = (yv[r] == c);
          cs[c][0] += msk ? v0 : 0.f;
          cs[c][1] += msk ? v1 : 0.f;
        }
      }
    }
  }
  #pragma unroll
  for (int c = 0; c < NC; ++c)
    #pragma unroll
    for (int n = 0; n < 2; ++n){
      cs[c][n] += __shfl_xor(cs[c][n], 16);
      cs[c][n] += __shfl_xor(cs[c][n], 32);
    }
  if (lane < 16){
    size_t gb = (size_t)(blk & (NREP-1))*5120 + colblk*128 + wc*32 + ln;
    #pragma unroll
    for (int c = 0; c < NC; ++c){
      atomicAdd(&gsum[gb + c*512],      cs[c][0]);
      atomicAdd(&gsum[gb + c*512 + 16], cs[c][1]);
    }
  }

  float* red = (float*)ldsd;               // dead resU region
  if (lane == 0) red[wv] = sumsq;
  __syncthreads();
  if (t == 0){
    float s = 0.f;
    #pragma unroll
    for (int i=0;i<8;++i) s += red[i];
    atomicAdd(&scal[SCAL_SUMSQ + (blk & (NREP-1))], s);
  }
  // copy x4 LDS -> global (16B stores): 32 tiles
  #pragma unroll
  for (int r = 0; r < 4; ++r){
    int o = r*512 + t;
    int tile = o >> 6, off16 = o & 63;
    int Il = tile >> 2, Cl = tile & 3;
    size_t Ig = (size_t)rowblk*8 + Il;
    int Cg = colblk*4 + Cl;
    *(short8*)&x4T[((Ig*16 + Cg) << 9) + off16*8] =
      *(const short8*)&x4U[(tile << 9) + off16*8];
  }
}

// ---------------------------------------------------------------------------
// 8-phase fine-interleaved K-loop (round-3 verified) — used by k_gemm3_head.
// Block = 256 rows x (128 cols x 2 matrices); 8 waves; BK=64; double-buffered
// 128KB LDS (per buffer: A 32KB @0, B0 16KB @32K, B1 16KB @48K).
// ---------------------------------------------------------------------------

#define BARRIER() __builtin_amdgcn_s_barrier()
#define LGKM0() do{ asm volatile("s_waitcnt lgkmcnt(0)" ::: "memory"); \
                    __builtin_amdgcn_sched_barrier(0); }while(0)

#define RA(AB, C) do{                                                         \
  _Pragma("unroll") for (int m_=0;m_<8;++m_)                                  \
    a[m_] = *(const short8*)((AB) + (((wr*8+m_)*2 + (C))<<10) + lane*16);     \
}while(0)

#define RB(AB, MAT, C) do{                                                    \
  _Pragma("unroll") for (int n_=0;n_<2;++n_)                                  \
    bb[n_] = *(const short8*)((AB) + 32768 + (MAT)*16384 +                    \
                              (((wc*2+n_)*2 + (C))<<10) + lane*16);           \
}while(0)

#define MM16(ACC) do{                                                         \
  __builtin_amdgcn_s_setprio(1);                                              \
  _Pragma("unroll") for (int n_=0;n_<2;++n_)                                  \
  _Pragma("unroll") for (int m_=0;m_<8;++m_)                                  \
    ACC[m_][n_] = __builtin_amdgcn_mfma_f32_16x16x32_bf16(a[m_], bb[n_], ACC[m_][n_], 0,0,0); \
  __builtin_amdgcn_s_setprio(0);                                              \
}while(0)

#define SA(KT, C) do{                                                         \
  char* d_ = ldsd + (((KT)&1) ? 65536 : 0);                                   \
  _Pragma("unroll") for (int r_=0;r_<2;++r_){                                 \
    int I_ = wv + r_*8;                                                       \
    GLL(xb + (((size_t)((rowblk*16 + I_)*16 + (KT)*2 + (C))) << 10) + lane*16,\
        d_ + ((I_*2 + (C)) << 10) + lane*16);                                 \
  } }while(0)

#define SB(KT, C) do{                                                         \
  char* d_ = ldsd + (((KT)&1) ? 65536 : 0) + 32768;                           \
  GLL(b0b + (((size_t)((colblk*8 + wv)*16 + (KT)*2 + (C))) << 10) + lane*16,  \
      d_ + ((wv*2 + (C)) << 10) + lane*16);                                   \
  GLL(b1b + (((size_t)((colblk*8 + wv)*16 + (KT)*2 + (C))) << 10) + lane*16,  \
      d_ + 16384 + ((wv*2 + (C)) << 10) + lane*16);                           \
}while(0)

#define KLOOP() do{                                                           \
  SA(0,0); SB(0,0); SA(0,1); SB(0,1); SA(1,0); SB(1,0); SA(1,1);              \
  asm volatile("s_waitcnt vmcnt(6)" ::: "memory");                            \
  __builtin_amdgcn_sched_barrier(0);                                          \
  BARRIER();                                                                  \
  _Pragma("unroll")                                                           \
  for (int i = 0; i < 4; ++i){                                                \
    int kt0 = 2*i, kt1 = 2*i+1;                                               \
    char* Ab0 = ldsd + ((kt0 & 1) ? 65536 : 0);                               \
    char* Ab1 = ldsd + ((kt1 & 1) ? 65536 : 0);                               \
    RA(Ab0, 0); RB(Ab0, 0, 0);                                                \
    SB(kt1, 1);                                                               \
    BARRIER(); LGKM0(); MM16(acc1);                                           \
    BARRIER();                                                                \
    RB(Ab0, 1, 0);                                                            \
    if (i < 3) SA(kt0+2, 0);                                                  \
    BARRIER(); LGKM0(); MM16(acc2);                                           \
    BARRIER();                                                                \
    RA(Ab0, 1); RB(Ab0, 0, 1);                                                \
    if (i < 3) SB(kt0+2, 0);                                                  \
    BARRIER(); LGKM0(); MM16(acc1);                                           \
    BARRIER();                                                                \
    RB(Ab0, 1, 1);                                                            \
    if (i < 3) SA(kt0+2, 1);                                                  \
    BARRIER(); LGKM0(); MM16(acc2);                                           \
    if (i < 3) { asm volatile("s_waitcnt vmcnt(6)" ::: "memory"); }           \
    else       { asm volatile("s_waitcnt vmcnt(0)" ::: "memory"); }           \
    __builtin_amdgcn_sched_barrier(0);                                        \
    BARRIER();                                                                \
    RA(Ab1, 0); RB(Ab1, 0, 0);                                                \
    if (i < 3) SB(kt0+2, 1);                                                  \
    BARRIER(); LGKM0(); MM16(acc1);                                           \
    BARRIER();                                                                \
    RB(Ab1, 1, 0);                                                            \
    if (i < 3) SA(kt1+2, 0);                                                  \
    BARRIER(); LGKM0(); MM16(acc2);                                           \
    BARRIER();                                                                \
    RA(Ab1, 1); RB(Ab1, 0, 1);                                                \
    if (i < 3) SB(kt1+2, 0);                                                  \
    BARRIER(); LGKM0(); MM16(acc1);                                           \
    BARRIER();                                                                \
    RB(Ab1, 1, 1);                                                            \
    if (i < 3) SA(kt1+2, 1);                                                  \
    BARRIER(); LGKM0(); MM16(acc2);                                           \
    if (i < 3) { asm volatile("s_waitcnt vmcnt(6)" ::: "memory");             \
                 __builtin_amdgcn_sched_barrier(0); }                         \
    BARRIER();                                                                \
  }                                                                           \
}while(0)

// K2: h = relu(x4 @ w); logits = h @ w1; CE/argmax/acc; LAST block finalizes.
__global__ __launch_bounds__(512, 2) void k_gemm3_head(
    const unsigned short* __restrict__ x4T,
    const unsigned short* __restrict__ wT,
    const unsigned short* __restrict__ w1T,
    const int* __restrict__ y,
    float* __restrict__ accb,
    float* __restrict__ out)
{
  extern __shared__ __align__(16) char ldsd[];   // 131072 dynamic
  __shared__ float redc[8], reda[8];
  __shared__ int lastB;

  float* scal = accb;

  int blk = blockIdx.x;
  int rowblk = blk;                              // 256 rows each
  const int colblk = 0;

  int t = threadIdx.x;
  int wv = t >> 6, lane = t & 63, ln = lane & 15, quad = lane >> 4;
  int wr = wv >> 2, wc = wv & 3;
  int rep = (blk ^ (blk >> 4)) & (NREP-1);

  const char* xb  = (const char*)x4T;
  const char* b0b = (const char*)wT;                       // w cols 0..127 (J 0..7)
  const char* b1b = (const char*)wT + (size_t)128*1024;    // w cols 128..255 (J 8..15)

  const f32x4 zv = {0.f,0.f,0.f,0.f};
  f32x4 acc1[8][2], acc2[8][2];
  #pragma unroll
  for (int m=0;m<8;++m){ acc1[m][0]=zv; acc1[m][1]=zv; acc2[m][0]=zv; acc2[m][1]=zv; }

  short8 a[8], bb[2];

  KLOOP();

  // w1 B-fragments from global (8KB, L2-resident)
  short8 bw1[8];
  #pragma unroll
  for (int Ck = 0; Ck < 8; ++Ck)
    bw1[Ck] = *(const short8*)&w1T[Ck*512 + lane*8];

  // h = relu(acc) fragment-tiled into the (dead) full 128KB LDS
  unsigned short* transH = (unsigned short*)ldsd;
  #pragma unroll
  for (int m = 0; m < 8; ++m){
    #pragma unroll
    for (int n = 0; n < 2; ++n){
      #pragma unroll
      for (int r = 0; r < 4; ++r){
        int slot = (quad*4 + r) | ((n*2 + (ln>>3)) << 4);
        int e = ln & 7;
        int IhA = wr*8 + m;
        transH[((IhA*8 + wc)     << 9) + slot*8 + e] = f2b(fmaxf(acc1[m][n][r], 0.f));
        transH[((IhA*8 + 4 + wc) << 9) + slot*8 + e] = f2b(fmaxf(acc2[m][n][r], 0.f));
      }
    }
  }
  __syncthreads();

  // logits: each wave handles row-tiles Ih = wv*2 + {0,1}
  f32x4 alog[2] = {zv, zv};
  #pragma unroll
  for (int ih = 0; ih < 2; ++ih){
    int Ih = wv*2 + ih;
    #pragma unroll
    for (int Ck = 0; Ck < 8; ++Ck){
      short8 af = *(const short8*)&transH[((Ih*8 + Ck) << 9) + lane*8];
      alog[ih] = __builtin_amdgcn_mfma_f32_16x16x32_bf16(af, bw1[Ck], alog[ih], 0,0,0);
    }
  }

  // CE/argmax: row = blk*256 + Ih*16 + quad*4 + r, class = ln
  float ce_l = 0.f, acc_l = 0.f;
  #pragma unroll
  for (int ih = 0; ih < 2; ++ih){
    #pragma unroll
    for (int r = 0; r < 4; ++r){
      int grow = blk*256 + (wv*2 + ih)*16 + quad*4 + r;
      int yv = y[grow];
      float lg = (ln < NC) ? alog[ih][r] : -1e30f;
      float m = lg; int mi = ln;
      #pragma unroll
      for (int mk = 1; mk < 16; mk <<= 1){
        float om = __shfl_xor(m, mk); int oi = __shfl_xor(mi, mk);
        if (om > m || (om == m && oi < mi)){ m = om; mi = oi; }
      }
      float e  = (ln < NC) ? __expf(lg - m) : 0.f;
      float sy = (ln == yv) ? lg : 0.f;
      #pragma unroll
      for (int mk = 1; mk < 16; mk <<= 1){ e += __shfl_xor(e, mk); sy += __shfl_xor(sy, mk); }
      float lse = m + __logf(e);
      if (ln == 0){ ce_l += (lse - sy); acc_l += (mi == yv) ? 1.f : 0.f; }
    }
  }
  ce_l  += __shfl_down(ce_l, 16);  acc_l += __shfl_down(acc_l, 16);
  ce_l  += __shfl_down(ce_l, 32);  acc_l += __shfl_down(acc_l, 32);
  if (lane == 0){ redc[wv] = ce_l; reda[wv] = acc_l; }
  __syncthreads();
  if (t == 0){
    float c = 0.f, aa = 0.f;
    #pragma unroll
    for (int i=0;i<8;++i){ c += redc[i]; aa += reda[i]; }
    atomicAdd(&scal[SCAL_CE  + rep], c);
    atomicAdd(&scal[SCAL_ACC + rep], aa);
    __threadfence();
    int prev = atomicAdd((int*)(scal + SCAL_CTR), 1);
    lastB = (prev == (int)gridDim.x - 1);
  }
  __syncthreads();
  if (!lastB) return;

  // ---- merged k_final: last block reduces gsum/gcnt/scal -> out
  {
    const float* gsum = accb + GSUM_OFF;
    const float* gcnt = accb + CNT_OFF;
    float contrib = 0.f;
    for (int idx = t; idx < 5120; idx += 512){
      float S = 0.f;
      #pragma unroll
      for (int r = 0; r < NREP; ++r) S += ald(&gsum[(size_t)r*5120 + idx]);
      int c = idx >> 9;
      float cnt = 0.f;
      #pragma unroll
      for (int r = 0; r < NREP; ++r) cnt += ald(&gcnt[r*16 + c]);
      contrib += S*S / fmaxf(cnt, 1.f);
    }
    for (int off = 32; off; off >>= 1) contrib += __shfl_down(contrib, off);
    __syncthreads();                  // redc reusable
    if (lane == 0) redc[wv] = contrib;
    __syncthreads();
    if (t == 0){
      float var2 = 0.f;
      #pragma unroll
      for (int i=0;i<8;++i) var2 += redc[i];
      float sumsq=0.f, ce=0.f, accv=0.f, l1=0.f;
      for (int r=0;r<NREP;++r){
        sumsq += ald(&scal[SCAL_SUMSQ+r]);
        ce    += ald(&scal[SCAL_CE+r]);
        accv  += ald(&scal[SCAL_ACC+r]);
        l1    += ald(&scal[SCAL_L1+r]);
      }
      float var_loss = sumsq - var2;
      out[0] = ce/(float)BATCH + 1e-4f*l1 + 1e-3f*var_loss;
      out[1] = accv/(float)BATCH;
    }
  }
}

extern "C" void kernel_launch(void* const* d_in, const int* in_sizes, int n_in,
                              void* d_out, int out_size, void* d_ws, size_t ws_size,
                              hipStream_t stream){
  (void)in_sizes; (void)n_in; (void)out_size; (void)ws_size;
  const float* x   = (const float*)d_in[0];
  const int*   y   = (const int*)d_in[1];
  const float* fc0 = (const float*)d_in[2];
  const float* fc1 = (const float*)d_in[3];
  const float* w   = (const float*)d_in[4];
  const float* w1  = (const float*)d_in[5];
  char* ws = (char*)d_ws;
  unsigned short* fc0T = (unsigned short*)(ws + OFF_FC0T);
  unsigned short* fc1T = (unsigned short*)(ws + OFF_FC1T);
  unsigned short* wT   = (unsigned short*)(ws + OFF_WT);
  unsigned short* xT   = (unsigned short*)(ws + OFF_XT);
  unsigned short* x4T  = (unsigned short*)(ws + OFF_X4T);
  unsigned short* w1T  = (unsigned short*)(ws + OFF_W1T);
  float* accb = (float*)(ws + OFF_ACC);

  static bool once = [](){
    hipFuncSetAttribute((const void*)k_gemm12,
                        hipFuncAttributeMaxDynamicSharedMemorySize, 65536);
    hipFuncSetAttribute((const void*)k_gemm3_head,
                        hipFuncAttributeMaxDynamicSharedMemorySize, 131072);
    return true;
  }();
  (void)once;

  k_setup<<<2481, 256, 0, stream>>>(x, fc0, fc1, w, w1, y, xT, fc0T, fc1T, wT, w1T, accb);
  k_gemm12<<<2048, 512, 65536, stream>>>(xT, fc0T, fc1T, y, x4T, accb);
  k_gemm3_head<<<256, 512, 131072, stream>>>(x4T, wT, w1T, y, accb, (float*)d_out);
}